// Round 9
// baseline (1401.695 us; speedup 1.0000x reference)
//
#include <hip/hip_runtime.h>
#include <hip/hip_fp16.h>
#include <stdint.h>

// BiLSTM 2-layer, B=64, T=1024, D=H=128.
// Round 15: r14 recovered the best scan (468us, VGPR 56) and fixed GEMM
// store coalescing + prep fusion: 1139us total = 936 scan + 203 non-scan.
// Scan is ~3% off its structural floor (620cyc MFMA pipe + ~350cyc h
// exchange + ~100 tail = ~1070 vs measured 1097) -- leave it byte-identical.
// This round: the GEMMs do 51 GFLOP (~25us at modest MFMA rates) but cost
// ~150us: the 64x64-tile k-loop pays 2 barriers per 16-word K-step (8/16
// barriers) with a vmcnt-drained staging round trip each step. New staging:
// ALL global loads issued at entry into regs (4-8 uint4/thr), then per
// 64-word chunk: write full tile to LDS [64][68] (2-way bank alias = free),
// ONE barrier, 16 back-to-back MFMA. GEMM1 = 1 barrier total, GEMM2 = 3.

#define T_SEQ 1024
#define B_SZ  64
#define M_TOT 65536  // B*T rows

typedef _Float16 h2_t __attribute__((ext_vector_type(2)));
typedef _Float16 f16x8 __attribute__((ext_vector_type(8)));
typedef float f32x4 __attribute__((ext_vector_type(4)));

__device__ inline uint32_t pack2(float a, float b) {
  uint16_t ua = __builtin_bit_cast(uint16_t, (_Float16)a);
  uint16_t ub = __builtin_bit_cast(uint16_t, (_Float16)b);
  return (uint32_t)ua | ((uint32_t)ub << 16);
}

// DPP quad_perm helper (compile-time ctrl). bcast lane q of quad = q*0x55.
template <int CTRL>
__device__ inline float dppf(float v) {
  return __builtin_bit_cast(
      float, __builtin_amdgcn_update_dpp(0, __builtin_bit_cast(int, v), CTRL,
                                         0xF, 0xF, true));
}

// ---------- fused prep ----------
// gp order everywhere: gp = 4j + p  <->  g = p*128 + j = ((gp&3)<<7)|(gp>>2).
// seg0 blocks [0,512):    whB   4 cells x [512 gp][64 kw] u32
// seg1 blocks [512,768):  bt1   2 cells x [512 gp][64 kw] u32   (Wih1 K=128)
// seg2 blocks [768,1280): bt2   2 cells x [512 gp][128 kw] u32  (Wih2 K=256)
// seg3 blocks [1280,1288): biascat [4 lc][512 gp] f32
__global__ void fused_prep(
    const float* __restrict__ Whh0, const float* __restrict__ Whh1,
    const float* __restrict__ Whh2, const float* __restrict__ Whh3,
    const float* __restrict__ Wih0, const float* __restrict__ Wih1,
    const float* __restrict__ Wih2, const float* __restrict__ Wih3,
    const float* __restrict__ bih0, const float* __restrict__ bih1,
    const float* __restrict__ bih2, const float* __restrict__ bih3,
    const float* __restrict__ bhh0, const float* __restrict__ bhh1,
    const float* __restrict__ bhh2, const float* __restrict__ bhh3,
    uint32_t* __restrict__ whbuf, uint32_t* __restrict__ btbuf1,
    uint32_t* __restrict__ btbuf2, float* __restrict__ biascat) {
  const int blk = blockIdx.x;
  const int tid = threadIdx.x;
  if (blk < 512) {
    int e = blk * 256 + tid;
    int c = e >> 15, e2 = e & 32767;
    const float* W = (c == 0) ? Whh0 : (c == 1) ? Whh1 : (c == 2) ? Whh2 : Whh3;
    int R = e2 >> 6, kw = e2 & 63;
    int g = ((R & 3) << 7) | (R >> 2);
    whbuf[c * 32768 + e2] = pack2(W[g * 128 + 2 * kw], W[g * 128 + 2 * kw + 1]);
  } else if (blk < 768) {
    int e = (blk - 512) * 256 + tid;
    int c = e >> 15, e2 = e & 32767;
    const float* W = c ? Wih1 : Wih0;
    int r = e2 >> 6, kw = e2 & 63;
    int g = ((r & 3) << 7) | (r >> 2);
    btbuf1[c * 32768 + e2] = pack2(W[g * 128 + 2 * kw], W[g * 128 + 2 * kw + 1]);
  } else if (blk < 1280) {
    int e = (blk - 768) * 256 + tid;
    int c = e >> 16, e2 = e & 65535;
    const float* W = c ? Wih3 : Wih2;
    int r = e2 >> 7, kw = e2 & 127;
    int g = ((r & 3) << 7) | (r >> 2);
    btbuf2[c * 65536 + e2] = pack2(W[g * 256 + 2 * kw], W[g * 256 + 2 * kw + 1]);
  } else {
    int e = (blk - 1280) * 256 + tid;  // < 2048
    int lc = e >> 9, gp = e & 511;
    const float* bi = (lc == 0) ? bih0 : (lc == 1) ? bih1 : (lc == 2) ? bih2 : bih3;
    const float* bh = (lc == 0) ? bhh0 : (lc == 1) ? bhh1 : (lc == 2) ? bhh2 : bhh3;
    int g = ((gp & 3) << 7) | (gp >> 2);
    biascat[e] = bi[g] + bh[g];
  }
}

// x [B,T,128] f32 -> packed f16x2 [M][64] u32
__global__ void prep_x(const float2* __restrict__ x2, uint32_t* __restrict__ xf16) {
  int idx = blockIdx.x * 256 + threadIdx.x;
  float2 v = x2[idx];
  xf16[idx] = pack2(v.x, v.y);
}

// ---------- xg GEMM: xg[cell][m][512 gp] f16 = A[m][:] . Wih^T + bias ----------
// A: [M][KW] u32 (f16x2, row-major). Bt rows gp-ordered -> contiguous stores.
// Full-tile staging: all global loads at entry (regs), one 64-word chunk in
// LDS at a time; 1 barrier (KW=64) or 3 (KW=128) instead of 8/16.
template <int KW>
__global__ __launch_bounds__(256) void xg_gemm(
    const uint32_t* __restrict__ A, const uint32_t* __restrict__ Bt,
    const float* __restrict__ biascat, uint16_t* __restrict__ xg) {
  const int n0 = blockIdx.x * 64;
  const int m0 = blockIdx.y * 64;
  const int tid = threadIdx.x;
  __shared__ uint32_t At[64][68];   // 64-word chunk, +4 pad: 2-way banks (free)
  __shared__ uint32_t Bts[64][68];
  const int lr = tid >> 2, lq = tid & 3;
  const int wave = tid >> 6, lane = tid & 63;
  const int wm = wave >> 1, wn = wave & 1;
  const int q = lane >> 4, ln16 = lane & 15;
  constexpr int NCH = KW / 64;

  // all chunks' tiles -> regs up front (latency fully overlapped)
  uint4 avr[NCH][4], bvr[NCH][4];
#pragma unroll
  for (int ch = 0; ch < NCH; ch++)
#pragma unroll
    for (int i = 0; i < 4; i++) {
      avr[ch][i] = *(const uint4*)&A[(size_t)(m0 + lr) * KW + ch * 64 + lq * 16 + 4 * i];
      bvr[ch][i] = *(const uint4*)&Bt[(size_t)(n0 + lr) * KW + ch * 64 + lq * 16 + 4 * i];
    }

  f32x4 acc[2][2] = {};
#pragma unroll
  for (int ch = 0; ch < NCH; ch++) {
    if (ch) __syncthreads();  // previous chunk's fragment reads complete
#pragma unroll
    for (int i = 0; i < 4; i++) {
      *(uint4*)&At[lr][lq * 16 + 4 * i] = avr[ch][i];
      *(uint4*)&Bts[lr][lq * 16 + 4 * i] = bvr[ch][i];
    }
    __syncthreads();
#pragma unroll
    for (int kt = 0; kt < 4; kt++)
#pragma unroll
      for (int mi = 0; mi < 2; mi++) {
        f16x8 af = *(const f16x8*)&At[wm * 32 + mi * 16 + ln16][kt * 16 + q * 4];
#pragma unroll
        for (int ni = 0; ni < 2; ni++) {
          f16x8 bf = *(const f16x8*)&Bts[wn * 32 + ni * 16 + ln16][kt * 16 + q * 4];
          acc[mi][ni] = __builtin_amdgcn_mfma_f32_16x16x32_f16(af, bf, acc[mi][ni], 0, 0, 0);
        }
      }
  }
  // D layout (verified m89/m91): col = lane&15, row = (lane>>4)*4 + reg
#pragma unroll
  for (int mi = 0; mi < 2; mi++)
#pragma unroll
    for (int ni = 0; ni < 2; ni++) {
      int n = n0 + wn * 32 + ni * 16 + ln16;
      float bs = biascat[n];
#pragma unroll
      for (int i = 0; i < 4; i++) {
        int m = m0 + wm * 32 + mi * 16 + q * 4 + i;
        float v = acc[mi][ni][i] + bs;
        xg[((size_t)(n >> 9) * M_TOT + m) * 512 + (n & 511)] =
            __builtin_bit_cast(uint16_t, (_Float16)v);
      }
    }
}

// ---------- scan: gates_t = xg_t + Whh.h_{t-1} via MFMA (round-11 exact) ----------
// 128 WGs (dir*64+b) x 512 thr. Wave w owns gates gp in [64w, 64w+64); lane
// l ends with z[gp = 64w+l] via the redundant-A-row trick. Tail: unit
// j = tid>>2, gate p = tid&3; quad DPP broadcast + redundant cell update.
// One raw lgkm-barrier per step; 8-slot xg prefetch pipeline (unclamped:
// signed row offsets stay inside the 2*M-row xg buffer for every (dir,b)).
template <bool FINAL>
__global__ __launch_bounds__(512, 2) void scan_kernel(
    const uint16_t* __restrict__ xg, const uint32_t* __restrict__ whB,
    uint16_t* __restrict__ hout, float* __restrict__ fout) {
  const int tid = threadIdx.x;
  const int j = tid >> 2;   // hidden unit 0..127
  const int p = tid & 3;    // gate selector (i,f,g,o)
  const int w = tid >> 6;   // wave 0..7
  const int lane = tid & 63;
  const int q = lane >> 4;  // 16-lane group 0..3
  const int ln16 = lane & 15;
  const int b = blockIdx.x & 63;
  const int dir = blockIdx.x >> 6;

  __shared__ __align__(16) uint32_t hbuf[2][64];  // [parity][h f16x2]

  // B-fragments of Whh: wb[nt][kt], lane l holds whB row gp=64w+16nt+ln16,
  // k-words 16kt+4q..+4.
  f16x8 wb[4][4];
  {
    const uint32_t* wp = whB + (size_t)dir * 512 * 64;
#pragma unroll
    for (int nt = 0; nt < 4; nt++)
#pragma unroll
      for (int kt = 0; kt < 4; kt++)
        wb[nt][kt] = *(const f16x8*)&wp[(64 * w + 16 * nt + ln16) * 64 + 16 * kt + 4 * q];
  }
#pragma unroll
  for (int nt = 0; nt < 4; nt++)
#pragma unroll
    for (int kt = 0; kt < 4; kt++) asm volatile("" : "+v"(wb[nt][kt]));

  // per-thread gate constants: lane p==2 computes tanh = 2*sigmoid(2z)-1
  const float kmul = (p == 2) ? (-2.0f * 1.44269504f) : -1.44269504f;
  const float gm = (p == 2) ? 2.0f : 1.0f;
  const float gb = (p == 2) ? -1.0f : 0.0f;

  const uint16_t* xgp = xg + ((size_t)dir * M_TOT + (size_t)b * T_SEQ) * 512 + tid;

  if (tid < 64) hbuf[0][tid] = 0u;
  float c = 0.0f;
  const f32x4 zero4 = {0.0f, 0.0f, 0.0f, 0.0f};

  // 8-slot prefetch pipeline: slot(s) = s&7; prologue fills steps 0..3.
  uint16_t xr[8];
#pragma unroll
  for (int k = 0; k < 4; k++) {
    const int tk = dir ? (T_SEQ - 1 - k) : k;
    xr[k] = xgp[(size_t)tk * 512];
  }
  __syncthreads();  // prologue: full drain once is fine

  for (int s0 = 0; s0 < T_SEQ; s0 += 8) {
    // re-pin weights each outer iter: forbids spill/remat
#pragma unroll
    for (int nt = 0; nt < 4; nt++)
#pragma unroll
      for (int kt = 0; kt < 4; kt++) asm volatile("" : "+v"(wb[nt][kt]));
#pragma unroll
    for (int k = 0; k < 8; k++) {
      const int s = s0 + k;
      const int par = k & 1;

      // issue prefetch for step s+4 into slot (k+4)&7 (unconditional,
      // unclamped: rows provably stay inside the 2*M_TOT-row buffer)
      {
        const int tn = dir ? (T_SEQ - 1 - (s + 4)) : (s + 4);
        xr[(k + 4) & 7] = *(xgp + (ptrdiff_t)tn * 512);
      }

      // MFMA matvec: A-frag rows all identical = h (each 16-lane group reads
      // the same 16B h slice); acc[nt] accumulates over the 4 K-tiles.
      const uint4* hb4 = (const uint4*)&hbuf[par][0];  // 16 x uint4
      f32x4 a0, a1, a2, a3;
      {
        f16x8 hk = __builtin_bit_cast(f16x8, hb4[q]);
        a0 = __builtin_amdgcn_mfma_f32_16x16x32_f16(hk, wb[0][0], zero4, 0, 0, 0);
        a1 = __builtin_amdgcn_mfma_f32_16x16x32_f16(hk, wb[1][0], zero4, 0, 0, 0);
        a2 = __builtin_amdgcn_mfma_f32_16x16x32_f16(hk, wb[2][0], zero4, 0, 0, 0);
        a3 = __builtin_amdgcn_mfma_f32_16x16x32_f16(hk, wb[3][0], zero4, 0, 0, 0);
      }
#pragma unroll
      for (int kt = 1; kt < 4; kt++) {
        f16x8 hk = __builtin_bit_cast(f16x8, hb4[kt * 4 + q]);
        a0 = __builtin_amdgcn_mfma_f32_16x16x32_f16(hk, wb[0][kt], a0, 0, 0, 0);
        a1 = __builtin_amdgcn_mfma_f32_16x16x32_f16(hk, wb[1][kt], a1, 0, 0, 0);
        a2 = __builtin_amdgcn_mfma_f32_16x16x32_f16(hk, wb[2][kt], a2, 0, 0, 0);
        a3 = __builtin_amdgcn_mfma_f32_16x16x32_f16(hk, wb[3][kt], a3, 0, 0, 0);
      }
      // all C rows identical -> lane l's gate (gp = 64w+l) sits in acc[q][0]
      float zs = (q & 2) ? ((q & 1) ? a3[0] : a2[0]) : ((q & 1) ? a1[0] : a0[0]);

      // fold in this lane's own xg term (counted vmcnt lands here)
      float z = zs + (float)__builtin_bit_cast(_Float16, xr[k]);

      // one transcendental per lane; tanh via sigmoid identity for p==2
      float e = __builtin_amdgcn_exp2f(z * kmul);
      float sg = __builtin_amdgcn_rcpf(1.0f + e);
      float gv = __builtin_fmaf(sg, gm, gb);

      // quad broadcast: every lane gets i,f,g,o (bitwise identical in quad)
      float gi = dppf<0x00>(gv);
      float gf = dppf<0x55>(gv);
      float gg = dppf<0xAA>(gv);
      float go = dppf<0xFF>(gv);

      c = __builtin_fmaf(gf, c, gi * gg);
      float ec = __builtin_amdgcn_exp2f(c * (-2.0f * 1.44269504f));
      float th = __builtin_fmaf(2.0f, __builtin_amdgcn_rcpf(1.0f + ec), -1.0f);
      float h = go * th;

      if (p == 0) {
        const int t = dir ? (T_SEQ - 1 - s) : s;
        uint16_t hu = __builtin_bit_cast(uint16_t, (_Float16)h);
        ((uint16_t*)(&hbuf[par ^ 1][0]))[j] = hu;
        if (FINAL) {
          fout[(size_t)(b * T_SEQ + t) * 256 + dir * 128 + j] = h;
        } else {
          hout[(size_t)(b * T_SEQ + t) * 256 + dir * 128 + j] = hu;
        }
      }
      // RAW barrier: order ONLY the LDS h-write (lgkmcnt), leave the global
      // prefetch loads / output stores in flight (counted vmcnt at use).
      asm volatile("s_waitcnt lgkmcnt(0)" ::: "memory");
      __builtin_amdgcn_s_barrier();
      asm volatile("" ::: "memory");  // nothing hoists above the barrier
    }
  }
}

extern "C" void kernel_launch(void* const* d_in, const int* in_sizes, int n_in,
                              void* d_out, int out_size, void* d_ws, size_t ws_size,
                              hipStream_t stream) {
  const float* x = (const float*)d_in[0];
  const float* Wih_fw1 = (const float*)d_in[2];
  const float* Whh_fw1 = (const float*)d_in[3];
  const float* bih_fw1 = (const float*)d_in[4];
  const float* bhh_fw1 = (const float*)d_in[5];
  const float* Wih_bw1 = (const float*)d_in[6];
  const float* Whh_bw1 = (const float*)d_in[7];
  const float* bih_bw1 = (const float*)d_in[8];
  const float* bhh_bw1 = (const float*)d_in[9];
  const float* Wih_fw2 = (const float*)d_in[10];
  const float* Whh_fw2 = (const float*)d_in[11];
  const float* bih_fw2 = (const float*)d_in[12];
  const float* bhh_fw2 = (const float*)d_in[13];
  const float* Wih_bw2 = (const float*)d_in[14];
  const float* Whh_bw2 = (const float*)d_in[15];
  const float* bih_bw2 = (const float*)d_in[16];
  const float* bhh_bw2 = (const float*)d_in[17];

  uint8_t* ws = (uint8_t*)d_ws;
  // ws layout (bytes):
  //   0        : whbuf   [4 cells][512 gp][64 kw] u32   512 KB
  //   524288   : btbuf1  [2 cells][512 gp][64]  u32     256 KB
  //   786432   : btbuf2  [2 cells][512 gp][128] u32     512 KB
  //   1310720  : biascat [4 lc][512 gp] f32               8 KB
  //   2097152  : xf16    [M][64] u32                     16 MB
  //   18874368 : out1    [M][256] u16                    32 MB
  //   52428800 : xg      [2][M][512] f16                128 MB
  uint32_t* whbuf = (uint32_t*)(ws + 0);
  uint32_t* btbuf1 = (uint32_t*)(ws + 524288);
  uint32_t* btbuf2 = (uint32_t*)(ws + 786432);
  float* biascat = (float*)(ws + 1310720);
  uint32_t* xf16 = (uint32_t*)(ws + 2097152);
  uint16_t* out1 = (uint16_t*)(ws + 18874368);
  uint16_t* xgbuf = (uint16_t*)(ws + 52428800);
  float* fout = (float*)d_out;

  // --- one fused prep for all weights/biases + x packing ---
  fused_prep<<<1288, 256, 0, stream>>>(
      Whh_fw1, Whh_bw1, Whh_fw2, Whh_bw2,
      Wih_fw1, Wih_bw1, Wih_fw2, Wih_bw2,
      bih_fw1, bih_bw1, bih_fw2, bih_bw2,
      bhh_fw1, bhh_bw1, bhh_fw2, bhh_bw2,
      whbuf, btbuf1, btbuf2, biascat);
  prep_x<<<(B_SZ * T_SEQ * 64) / 256, 256, 0, stream>>>((const float2*)x, xf16);

  // --- layer 1: xg GEMM + scan ---
  xg_gemm<64><<<dim3(16, 1024), 256, 0, stream>>>(xf16, btbuf1, biascat, xgbuf);
  scan_kernel<false><<<128, 512, 0, stream>>>(xgbuf, whbuf + 0, out1, nullptr);

  // --- layer 2: xg GEMM (reads out1) + scan -> d_out ---
  xg_gemm<128><<<dim3(16, 1024), 256, 0, stream>>>((const uint32_t*)out1, btbuf2,
                                                   biascat + 1024, xgbuf);
  scan_kernel<true><<<128, 512, 0, stream>>>(xgbuf, whbuf + 2 * 32768, nullptr, fout);
}